// Round 1
// baseline (8711.231 us; speedup 1.0000x reference)
//
#include <hip/hip_runtime.h>

// ---------------------------------------------------------------------------
// LSTM recurrence, T=2048, B=32, D=H=512.
//   Phase 1: xp = input @ W_x + b   (bf16 MFMA GEMM) -> ws (bf16)
//   Phase 2: persistent recurrence, 64 WGs = 2 independent batch-groups(16) x
//            32 h-slices. Per-batch-group m [16][512] double-buffered in
//            global (MFMA A-fragment layout), exchanged via RELAXED+AGENT
//            accesses. Per-WAVE flag publication (vmcnt(0) drain + relaxed
//            store); every wave polls its group's 128 packed flags. One
//            __syncthreads per step (LDS staging). out-store issued after
//            flag publication (HBM ack off the critical path).
// ---------------------------------------------------------------------------

typedef __bf16  bf16x8 __attribute__((ext_vector_type(8)));
typedef float   f32x4  __attribute__((ext_vector_type(4)));

__device__ __forceinline__ unsigned short f2bf(float f) {
  unsigned u = __builtin_bit_cast(unsigned, f);
  u += 0x7fffu + ((u >> 16) & 1u);   // round-to-nearest-even
  return (unsigned short)(u >> 16);
}
__device__ __forceinline__ float bf2f(unsigned short h) {
  unsigned u = ((unsigned)h) << 16;
  return __builtin_bit_cast(float, u);
}
__device__ __forceinline__ float fast_sigmoid(float x) {
  return __builtin_amdgcn_rcpf(1.0f + __expf(-x));
}
__device__ __forceinline__ float fast_tanh(float x) {
  return 2.0f * __builtin_amdgcn_rcpf(1.0f + __expf(-2.0f * x)) - 1.0f;
}

// ---------------------------------------------------------------------------
// Transpose + fp32->bf16 convert: W [512][2048] -> WT [2048][512] bf16.
// ---------------------------------------------------------------------------
__global__ __launch_bounds__(256) void transpose_cvt(
    const float* __restrict__ Wx, const float* __restrict__ Wh,
    unsigned short* __restrict__ WxT, unsigned short* __restrict__ WhT) {
  const float* src = blockIdx.z ? Wh : Wx;
  unsigned short* dst = blockIdx.z ? WhT : WxT;
  __shared__ float tile[32][33];
  const int n0 = blockIdx.x * 32, k0 = blockIdx.y * 32;
  const int t = threadIdx.x;
  {
    const int kk = t >> 3, nn = (t & 7) * 4;
    float4 v = *(const float4*)(src + (size_t)(k0 + kk) * 2048 + n0 + nn);
    tile[kk][nn + 0] = v.x; tile[kk][nn + 1] = v.y;
    tile[kk][nn + 2] = v.z; tile[kk][nn + 3] = v.w;
  }
  __syncthreads();
  {
    const int n = t >> 3, k4 = (t & 7) * 4;
    ushort4 o;
    o.x = f2bf(tile[k4 + 0][n]); o.y = f2bf(tile[k4 + 1][n]);
    o.z = f2bf(tile[k4 + 2][n]); o.w = f2bf(tile[k4 + 3][n]);
    *(ushort4*)(dst + (size_t)(n0 + n) * 512 + k0 + k4) = o;
  }
}

// ---------------------------------------------------------------------------
// xp = input @ W_x + b, output bf16 [65536][2048]. 128x128 tile, 4 waves.
// ---------------------------------------------------------------------------
__global__ __launch_bounds__(256) void gemm_xproj(
    const float* __restrict__ A, const unsigned short* __restrict__ BT,
    const float* __restrict__ bias, unsigned short* __restrict__ C) {
  __shared__ unsigned short As[128 * 32];
  __shared__ unsigned short Bs[128 * 32];
  const int m0 = blockIdx.x * 128, n0 = blockIdx.y * 128;
  const int tid = threadIdx.x, w = tid >> 6, lane = tid & 63;
  const int q = lane >> 4, r = lane & 15;
  const int wm = (w >> 1) * 64, wn = (w & 1) * 64;
  const int srow = tid >> 1, shalf = tid & 1;

  f32x4 acc[4][4] = {};

  for (int kt = 0; kt < 16; ++kt) {
    const int k0 = kt * 32;
    {
      const float* ap = A + (size_t)(m0 + srow) * 512 + k0 + shalf * 16;
#pragma unroll
      for (int c = 0; c < 4; ++c) {
        float4 v = *(const float4*)(ap + c * 4);
        ushort4 h;
        h.x = f2bf(v.x); h.y = f2bf(v.y); h.z = f2bf(v.z); h.w = f2bf(v.w);
        *(ushort4*)&As[srow * 32 + shalf * 16 + c * 4] = h;
      }
    }
    {
      const unsigned short* bp = BT + (size_t)(n0 + srow) * 512 + k0 + shalf * 16;
#pragma unroll
      for (int c2 = 0; c2 < 2; ++c2)
        *(uint4*)&Bs[srow * 32 + shalf * 16 + c2 * 8] = *(const uint4*)(bp + c2 * 8);
    }
    __syncthreads();
    bf16x8 af[4], bfr[4];
#pragma unroll
    for (int i = 0; i < 4; ++i)
      af[i] = *(const bf16x8*)&As[(wm + i * 16 + r) * 32 + q * 8];
#pragma unroll
    for (int j = 0; j < 4; ++j)
      bfr[j] = *(const bf16x8*)&Bs[(wn + j * 16 + r) * 32 + q * 8];
#pragma unroll
    for (int i = 0; i < 4; ++i)
#pragma unroll
      for (int j = 0; j < 4; ++j)
        acc[i][j] = __builtin_amdgcn_mfma_f32_16x16x32_bf16(af[i], bfr[j], acc[i][j], 0, 0, 0);
    __syncthreads();
  }
#pragma unroll
  for (int j = 0; j < 4; ++j) {
    const int col = n0 + wn + j * 16 + r;
    const float bv = bias[col];
#pragma unroll
    for (int i = 0; i < 4; ++i) {
#pragma unroll
      for (int e = 0; e < 4; ++e) {
        const int row = m0 + wm + i * 16 + q * 4 + e;
        C[(size_t)row * 2048 + col] = f2bf(acc[i][j][e] + bv);
      }
    }
  }
}

// ---------------------------------------------------------------------------
// Persistent recurrence: 64 WGs x 256 threads, 2 independent batch groups.
//   grp = bid>>5 owns batch rows [grp*16, grp*16+16); g = bid&31 owns
//   h in [g*16, (g+1)*16). Wave w, lane(q=lane>>4, r=lane&15):
//     GEMM cols:    typ = r&3, hlb = r>>2, n_glob = typ*512 + g*16 + w*4 + hlb
//     cell (1/lane): erow = lane>>2, ehl = lane&3, h = g*16 + w*4 + ehl
//   m buffer per group [16][512] bf16 in A-fragment layout: element (row,k) at
//     byte (k>>5)*1024 + (((k>>3)&3)*16 + row)*16 + (k&7)*2
// ---------------------------------------------------------------------------
__global__ __launch_bounds__(256, 1) void lstm_rec(
    const unsigned short* __restrict__ xp,   // [65536][2048] bf16
    const float* __restrict__ pads,          // [2048*32]
    const unsigned short* __restrict__ WhT,  // [2048][512] bf16
    float* __restrict__ out,                 // [T*B*H + 2*B*H] fp32
    unsigned short* __restrict__ mbuf,       // [2 grp][2 parity][16 KB]
    unsigned int* __restrict__ flags) {      // [2 grp][128] per-wave flags
  const int bid = blockIdx.x, grp = bid >> 5, g = bid & 31;
  const int tid = threadIdx.x, w = tid >> 6, lane = tid & 63;
  const int q = lane >> 4, r = lane & 15;

  __shared__ unsigned long long mAq[2048];   // 16 KB staged m (A-frag layout)
  __shared__ float gsm[4 * 16 * 17];         // per-wave private transpose tile

  // ---- register-resident W_h B-fragments (16 cols/wave, arbitrary col map) ----
  const int typ_b = r & 3, hl_b = r >> 2;
  const int n_glob = typ_b * 512 + g * 16 + w * 4 + hl_b;
  bf16x8 bfrag[16];
#pragma unroll
  for (int kt = 0; kt < 16; ++kt)
    bfrag[kt] = *(const bf16x8*)(WhT + (size_t)n_glob * 512 + kt * 32 + q * 8);

  // ---- elementwise ownership: 1 cell per lane ----
  const int erow = lane >> 2, ehl = lane & 3;
  const int h = g * 16 + w * 4 + ehl;        // local h (== k index into m)
  const int brow = grp * 16 + erow;          // global batch row
  const size_t mwoff = (size_t)(h >> 5) * 1024 +
                       (size_t)(((h >> 3) & 3) * 16 + erow) * 16 +
                       (size_t)(h & 7) * 2;
  float cst = 0.f, mst = 0.f;

  const unsigned wid = (unsigned)(g * 4 + w);
  unsigned int* const gflags = flags + grp * 128;
  unsigned short* const gbuf = mbuf + (size_t)grp * 16384;  // 32 KB/group (2 parities)

  // prefetch xp/pads for t=0
  float pf_p = pads[brow];
  unsigned short pf_x[4];
#pragma unroll
  for (int ty = 0; ty < 4; ++ty)
    pf_x[ty] = xp[(size_t)brow * 2048 + ty * 512 + h];

  for (int t = 0; t < 2048; ++t) {
    // ---- stage m_t into LDS: 8x 8B agent loads, b64 LDS writes (2-way free) ----
    const unsigned long long* mr =
        (const unsigned long long*)(gbuf + ((t & 1) ? 8192 : 0));
    unsigned long long mt[8];
#pragma unroll
    for (int c = 0; c < 8; ++c)
      mt[c] = __hip_atomic_load(mr + c * 256 + tid, __ATOMIC_RELAXED,
                                __HIP_MEMORY_SCOPE_AGENT);
#pragma unroll
    for (int c = 0; c < 8; ++c)
      mAq[c * 256 + tid] = mt[c];
    __syncthreads();

    // ---- GEMM: gates(cols of this wave) = m[16,512] @ W_h, 4 acc chains ----
    f32x4 ac[4] = {};
#pragma unroll
    for (int kt = 0; kt < 16; ++kt) {
      bf16x8 a = *(const bf16x8*)((const char*)mAq + kt * 1024 + lane * 16);
      ac[kt & 3] = __builtin_amdgcn_mfma_f32_16x16x32_bf16(a, bfrag[kt], ac[kt & 3], 0, 0, 0);
    }
    const f32x4 acc = (ac[0] + ac[1]) + (ac[2] + ac[3]);

    // ---- transpose within wave via private LDS (no barrier needed) ----
    float* gw = gsm + w * 272;
#pragma unroll
    for (int e = 0; e < 4; ++e)
      gw[r * 17 + q * 4 + e] = acc[e];
    const float gt0 = gw[(ehl * 4 + 0) * 17 + erow];
    const float gt1 = gw[(ehl * 4 + 1) * 17 + erow];
    const float gt2 = gw[(ehl * 4 + 2) * 17 + erow];
    const float gt3 = gw[(ehl * 4 + 3) * 17 + erow];

    // ---- elementwise LSTM cell ----
    const float p  = pf_p;
    const float xi = bf2f(pf_x[0]), xf = bf2f(pf_x[1]);
    const float xg = bf2f(pf_x[2]), xo = bf2f(pf_x[3]);
    const float si = fast_sigmoid(gt0 + xi), sf = fast_sigmoid(gt1 + xf);
    const float tg = fast_tanh(gt2 + xg),    so = fast_sigmoid(gt3 + xo);
    const float cn = sf * cst + si * tg;
    const float mn = so * fast_tanh(cn);
    const float m2 = mn + p * (mst - mn);
    const float c2 = cn + p * (cst - cn);
    mst = m2; cst = c2;

    if (t < 2047) {
      // ---- publish m_{t+1}: even-ehl lanes pack (h, h+1) as one dword ----
      unsigned short* mw = gbuf + (((t + 1) & 1) ? 8192 : 0);
      const unsigned mu = (unsigned)f2bf(m2);
      const unsigned hi = (unsigned)__shfl_down((int)mu, 1);
      if ((lane & 1) == 0)
        __hip_atomic_store((unsigned*)((char*)mw + mwoff), mu | (hi << 16),
                           __ATOMIC_RELAXED, __HIP_MEMORY_SCOPE_AGENT);
      // wave-level drain: m stores visible at LLC before flag store
      asm volatile("s_waitcnt vmcnt(0)" ::: "memory");
      if (lane == 0)
        __hip_atomic_store(gflags + wid, (unsigned)(t + 1),
                           __ATOMIC_RELAXED, __HIP_MEMORY_SCOPE_AGENT);
    }

    // ---- out store AFTER flag publication (HBM ack off critical path) ----
    out[(size_t)t * 16384 + (size_t)brow * 512 + h] = m2;

    if (t < 2047) {
      // ---- prefetch xp/pads for t+1 (completes under the poll) ----
      pf_p = pads[(t + 1) * 32 + brow];
#pragma unroll
      for (int ty = 0; ty < 4; ++ty)
        pf_x[ty] = xp[(size_t)((t + 1) * 32 + brow) * 2048 + ty * 512 + h];

      // ---- per-wave poll: all 128 group flags >= t+1 ----
      const unsigned tgt = (unsigned)(t + 1);
      for (;;) {
        const unsigned v0 = __hip_atomic_load(gflags + lane, __ATOMIC_RELAXED,
                                              __HIP_MEMORY_SCOPE_AGENT);
        const unsigned v1 = __hip_atomic_load(gflags + 64 + lane, __ATOMIC_RELAXED,
                                              __HIP_MEMORY_SCOPE_AGENT);
        if (__ballot((v0 < tgt) || (v1 < tgt)) == 0ull) break;
        __builtin_amdgcn_s_sleep(1);
      }
    }
  }

  // final (m_f, c_f)
  {
    float* mo = out + 33554432 + (size_t)brow * 512 + h;
    mo[0]     = mst;
    mo[16384] = cst;
  }
}

// ---------------------------------------------------------------------------
// Workspace layout (bytes):
//   xp    @ 0          : 268435456
//   WxT   @ 268435456  : 2097152
//   WhT   @ 270532608  : 2097152
//   mbuf  @ 272629760  : 65536   (2 groups x 2 parities x 16 KB)
//   flags @ 272695296  : 2048    (2 groups x 128 dwords used)
// ---------------------------------------------------------------------------
extern "C" void kernel_launch(void* const* d_in, const int* in_sizes, int n_in,
                              void* d_out, int out_size, void* d_ws, size_t ws_size,
                              hipStream_t stream) {
  (void)in_sizes; (void)n_in; (void)out_size; (void)ws_size;
  const float* input = (const float*)d_in[0];
  const float* pads  = (const float*)d_in[1];
  const float* Wx    = (const float*)d_in[2];
  const float* Wh    = (const float*)d_in[3];
  const float* bias  = (const float*)d_in[4];
  float* out = (float*)d_out;

  char* ws = (char*)d_ws;
  unsigned short* xp  = (unsigned short*)(ws);
  unsigned short* WxT = (unsigned short*)(ws + 268435456);
  unsigned short* WhT = (unsigned short*)(ws + 270532608);
  unsigned short* mb  = (unsigned short*)(ws + 272629760);
  unsigned int* flags = (unsigned int*)(ws + 272695296);

  hipMemsetAsync(ws + 272629760, 0, 65536 + 2048, stream);

  transpose_cvt<<<dim3(64, 16, 2), 256, 0, stream>>>(Wx, Wh, WxT, WhT);
  gemm_xproj<<<dim3(512, 16), 256, 0, stream>>>(input, WxT, bias, xp);
  lstm_rec<<<64, 256, 0, stream>>>(xp, pads, WhT, out, mb, flags);
}